// Round 5
// baseline (349.478 us; speedup 1.0000x reference)
//
#include <hip/hip_runtime.h>

#define B_ 8
#define N_ 2048
#define D_ 64

typedef __attribute__((ext_vector_type(8))) short bf16x8;
typedef __attribute__((ext_vector_type(4))) float f32x4;

__device__ inline unsigned short f32_bf16_rne(float f) {
    unsigned u = __float_as_uint(f);
    u += 0x7fffu + ((u >> 16) & 1u);
    return (unsigned short)(u >> 16);
}

// packed f32x2 -> bf16x2 (RNE), one instruction; no builtin on gfx950 (T12)
__device__ inline unsigned cvt_pk_bf16(float lo, float hi) {
    unsigned r;
    asm("v_cvt_pk_bf16_f32 %0, %1, %2" : "=v"(r) : "v"(lo), "v"(hi));
    return r;
}

// Kernel 0: pack int32 0/1 masks into bitmasks. One shot, straight-line:
// thread g owns ints [32g, 32g+32) of each mask -> one uint32 per mask.
// All 16 independent int4 loads are issued UP FRONT (256 B/thread in flight;
// launch_bounds(256,4) gives the allocator 128 VGPRs) and sched_group_barrier
// pins {16 x VMEM_READ -> VALU} so the occupancy heuristic can't re-serialize
// them (round-3 failure: VGPR_Count=16, ~2 loads in flight, 1.4 TB/s).
// Bit k of word g = mask[g*32+k] & 1 (inputs are {0,1}; ==1 equivalent).
__global__ __launch_bounds__(256, 4) void pack_kernel(
    const int* __restrict__ mA, const int* __restrict__ mJ,
    unsigned* __restrict__ cA, unsigned* __restrict__ cJ) {
    const size_t g = (size_t)blockIdx.x * 256 + threadIdx.x;  // word index
    const int4* pA = (const int4*)(mA + g * 32);
    const int4* pJ = (const int4*)(mJ + g * 32);
    int4 a[8], j[8];
#pragma unroll
    for (int k = 0; k < 8; k++) a[k] = pA[k];
#pragma unroll
    for (int k = 0; k < 8; k++) j[k] = pJ[k];
    // T19: force all 16 VMEM reads to issue before the pack VALU cluster
    __builtin_amdgcn_sched_group_barrier(0x020, 16, 0);   // VMEM_READ x16
    __builtin_amdgcn_sched_group_barrier(0x002, 256, 0);  // VALU cluster

    unsigned wa = 0, wj = 0;
#pragma unroll
    for (int k = 0; k < 8; k++) {
        wa |= ((unsigned)(a[k].x & 1) << (4 * k)) |
              ((unsigned)(a[k].y & 1) << (4 * k + 1)) |
              ((unsigned)(a[k].z & 1) << (4 * k + 2)) |
              ((unsigned)(a[k].w & 1) << (4 * k + 3));
        wj |= ((unsigned)(j[k].x & 1) << (4 * k)) |
              ((unsigned)(j[k].y & 1) << (4 * k + 1)) |
              ((unsigned)(j[k].z & 1) << (4 * k + 2)) |
              ((unsigned)(j[k].w & 1) << (4 * k + 3));
    }
    cA[g] = wa;
    cJ[g] = wj;
}

// Kernel A: h = feats @ W^T (fp32), a_src reduction, exp tables for the dst side,
// store hT[b][d][j] as bf16. 512 blocks x 256 threads; block = 32 rows of one batch.
__global__ __launch_bounds__(256) void prep_kernel(
    const float* __restrict__ feats, const float* __restrict__ W,
    const float* __restrict__ attn_src, const float* __restrict__ attn_dst,
    unsigned short* __restrict__ hT, float* __restrict__ a_src,
    float* __restrict__ F1, float* __restrict__ F2) {
    __shared__ float w_lds[64 * 65];          // padded: bank = (o+d)%32, conflict-free
    __shared__ float f_lds[32 * 64];
    __shared__ unsigned short hT_lds[64 * 40]; // row stride 40 ushorts = 80B (16B aligned)

    const int t = threadIdx.x;
    const int b = blockIdx.x >> 6;            // 64 row-tiles per batch
    const int rowbase = (blockIdx.x & 63) * 32;

    // cooperative load W (64x64) into padded LDS
#pragma unroll
    for (int k = 0; k < 4; k++) {
        int lin = (k * 256 + t) * 4;
        float4 v = *(const float4*)(W + lin);
        int o = lin >> 6, d = lin & 63;
        float* p = &w_lds[o * 65 + d];
        p[0] = v.x; p[1] = v.y; p[2] = v.z; p[3] = v.w;
    }
    // cooperative load feats tile (32x64), linear layout
#pragma unroll
    for (int k = 0; k < 2; k++) {
        int lin = (k * 256 + t) * 4;
        float4 v = *(const float4*)(feats + (size_t)(b * N_ + rowbase) * D_ + lin);
        float* p = &f_lds[lin];
        p[0] = v.x; p[1] = v.y; p[2] = v.z; p[3] = v.w;
    }
    __syncthreads();

    const int w = t >> 6;     // wave id: rows w*8 .. w*8+7
    const int o = t & 63;     // output channel
    float acc[8] = {0.f, 0.f, 0.f, 0.f, 0.f, 0.f, 0.f, 0.f};
#pragma unroll 8
    for (int d = 0; d < 64; d++) {
        float wv = w_lds[o * 65 + d];
#pragma unroll
        for (int rr = 0; rr < 8; rr++)
            acc[rr] = fmaf(f_lds[(w * 8 + rr) * 64 + d], wv, acc[rr]);
    }
    float as_ = attn_src[o], ad_ = attn_dst[o];
#pragma unroll
    for (int rr = 0; rr < 8; rr++) {
        int row = rowbase + w * 8 + rr;
        float s1 = acc[rr] * as_;
        float s2 = acc[rr] * ad_;
#pragma unroll
        for (int off = 32; off; off >>= 1) {
            s1 += __shfl_xor(s1, off);
            s2 += __shfl_xor(s2, off);
        }
        if (o == 0) {
            a_src[b * N_ + row] = s1;
            F1[b * N_ + row] = __expf(s2);         // exp(a_dst)
            F2[b * N_ + row] = __expf(0.2f * s2);  // exp(0.2*a_dst)
        }
        hT_lds[o * 40 + w * 8 + rr] = f32_bf16_rne(acc[rr]);
    }
    __syncthreads();
    // transposed store: hT[b][d][rowbase..rowbase+32)
    const int d = t >> 2, seg = t & 3;
    uint4 vv = *(const uint4*)(&hT_lds[d * 40 + seg * 8]);
    *(uint4*)(hT + ((size_t)(b * 64 + d) * N_ + rowbase + seg * 8)) = vv;
}

// Kernel B: masked dual-softmax attention via bf16 MFMA.
// Reads 1-bit packed masks: each lane pulls its whole 512-col slice (16 words
// per mask, L2-resident after pack_kernel) UP FRONT; per step the 8 predicate
// bits are a shift+mask of word[st]. Only per-step loads are F1/F2 (16 KB/batch,
// L1-resident) and hT (256 KB/batch, L2-resident). ~44 us in round 3.
__global__ __launch_bounds__(256, 3) void attn_kernel(
    const unsigned char* __restrict__ cmA, const unsigned char* __restrict__ cmJ,
    const int* __restrict__ batch_idxes,
    const unsigned short* __restrict__ hT, const float* __restrict__ a_src,
    const float* __restrict__ F1, const float* __restrict__ F2,
    const float* __restrict__ feats, const float* __restrict__ lambda_params,
    float* __restrict__ out) {
    __shared__ f32x4 redbuf[3][10][64];       // waves 1..3 partial state: 30 KB

    const int t = threadIdx.x;
    const int b = blockIdx.x >> 7;            // 128 row-tiles per batch
    const int rowbase = (blockIdx.x & 127) * 16;
    const int wid = t >> 6, lane = t & 63;
    const int m = lane & 15, q = lane >> 4;
    const int i_a = rowbase + m;              // A-fragment row this lane owns

    int bi = batch_idxes[b];
    bi = (bi < 0) ? 0 : ((bi >= B_) ? (B_ - 1) : bi);

    const int jb = wid * 512 + q * 8;         // lane's column base within the row
    const float* f1p = F1 + b * N_ + jb;
    const float* f2p = F2 + b * N_ + jb;
    const unsigned short* hp0 = hT + (size_t)b * 64 * N_ + (size_t)m * N_ + jb;
    const unsigned short* hp1 = hp0 + 16 * N_;
    const unsigned short* hp2 = hp0 + 32 * N_;
    const unsigned short* hp3 = hp0 + 48 * N_;

    // upfront bitmask load: 64 B per mask covers all 16 steps of this lane's slice
    union { uint4 v[4]; unsigned w[16]; } WA, WJ;
    {
        const uint4* pA = (const uint4*)(cmA + ((size_t)bi * N_ + i_a) * (N_ / 8) + wid * 64);
        const uint4* pJ = (const uint4*)(cmJ + ((size_t)bi * N_ + i_a) * (N_ / 8) + wid * 64);
        WA.v[0] = pA[0]; WA.v[1] = pA[1]; WA.v[2] = pA[2]; WA.v[3] = pA[3];
        WJ.v[0] = pJ[0]; WJ.v[1] = pJ[1]; WJ.v[2] = pJ[2]; WJ.v[3] = pJ[3];
    }

    const float s = a_src[b * N_ + i_a];
    const float cmpT = __expf(-s);            // exp(d) >= exp(-s)  <=>  e >= 0
    const float cT = __expf(-0.8f * s);       // exp(0.2e - s) = cT * exp(0.2 d)

    f32x4 accA[4], accJ[4], accZA, accZJ;
    const f32x4 z4 = {0.f, 0.f, 0.f, 0.f};
#pragma unroll
    for (int dd = 0; dd < 4; dd++) { accA[dd] = z4; accJ[dd] = z4; }
    accZA = z4; accZJ = z4;
    bf16x8 ones;
#pragma unroll
    for (int i = 0; i < 8; i++) ones[i] = (short)0x3F80;  // bf16(1.0)

#pragma unroll
    for (int st = 0; st < 16; st++) {
        const int off = st * 32;              // 128B/step immediate offsets
        float4 g0 = *(const float4*)(f1p + off);
        float4 g1 = *(const float4*)(f1p + off + 4);
        float4 h0 = *(const float4*)(f2p + off);
        float4 h1 = *(const float4*)(f2p + off + 4);
        bf16x8 fb0 = *(const bf16x8*)(hp0 + off);
        bf16x8 fb1 = *(const bf16x8*)(hp1 + off);
        bf16x8 fb2 = *(const bf16x8*)(hp2 + off);
        bf16x8 fb3 = *(const bf16x8*)(hp3 + off);

        float f1v[8] = {g0.x, g0.y, g0.z, g0.w, g1.x, g1.y, g1.z, g1.w};
        float f2v[8] = {h0.x, h0.y, h0.z, h0.w, h1.x, h1.y, h1.z, h1.w};
        const unsigned byteA = (WA.w[st] >> (q * 8)) & 0xffu;
        const unsigned byteJ = (WJ.w[st] >> (q * 8)) & 0xffu;

        unsigned ua[4], uj[4];
#pragma unroll
        for (int wp = 0; wp < 4; wp++) {
            float p0 = (f1v[2 * wp] >= cmpT) ? f1v[2 * wp] : cT * f2v[2 * wp];
            float p1 = (f1v[2 * wp + 1] >= cmpT) ? f1v[2 * wp + 1] : cT * f2v[2 * wp + 1];
            float pa0 = ((byteA >> (2 * wp)) & 1u) ? p0 : 0.f;
            float pa1 = ((byteA >> (2 * wp + 1)) & 1u) ? p1 : 0.f;
            float pj0 = ((byteJ >> (2 * wp)) & 1u) ? p0 : 0.f;
            float pj1 = ((byteJ >> (2 * wp + 1)) & 1u) ? p1 : 0.f;
            ua[wp] = cvt_pk_bf16(pa0, pa1);
            uj[wp] = cvt_pk_bf16(pj0, pj1);
        }
        union { uint4 u; bf16x8 v; } fa_, fj_;
        fa_.u = make_uint4(ua[0], ua[1], ua[2], ua[3]);
        fj_.u = make_uint4(uj[0], uj[1], uj[2], uj[3]);
        bf16x8 fa = fa_.v, fj = fj_.v;

        // softmax denominators ride the MFMA pipe (B = ones)
        accZA = __builtin_amdgcn_mfma_f32_16x16x32_bf16(fa, ones, accZA, 0, 0, 0);
        accZJ = __builtin_amdgcn_mfma_f32_16x16x32_bf16(fj, ones, accZJ, 0, 0, 0);
        accA[0] = __builtin_amdgcn_mfma_f32_16x16x32_bf16(fa, fb0, accA[0], 0, 0, 0);
        accJ[0] = __builtin_amdgcn_mfma_f32_16x16x32_bf16(fj, fb0, accJ[0], 0, 0, 0);
        accA[1] = __builtin_amdgcn_mfma_f32_16x16x32_bf16(fa, fb1, accA[1], 0, 0, 0);
        accJ[1] = __builtin_amdgcn_mfma_f32_16x16x32_bf16(fj, fb1, accJ[1], 0, 0, 0);
        accA[2] = __builtin_amdgcn_mfma_f32_16x16x32_bf16(fa, fb2, accA[2], 0, 0, 0);
        accJ[2] = __builtin_amdgcn_mfma_f32_16x16x32_bf16(fj, fb2, accJ[2], 0, 0, 0);
        accA[3] = __builtin_amdgcn_mfma_f32_16x16x32_bf16(fa, fb3, accA[3], 0, 0, 0);
        accJ[3] = __builtin_amdgcn_mfma_f32_16x16x32_bf16(fj, fb3, accJ[3], 0, 0, 0);
    }

    // cross-wave reduction of j-slice partials (40 f32 per lane = 10 f32x4 chunks)
    if (wid) {
#pragma unroll
        for (int c = 0; c < 4; c++) {
            redbuf[wid - 1][c][lane] = accA[c];
            redbuf[wid - 1][4 + c][lane] = accJ[c];
        }
        redbuf[wid - 1][8][lane] = accZA;
        redbuf[wid - 1][9][lane] = accZJ;
    }
    __syncthreads();
    if (wid == 0) {
#pragma unroll
        for (int wv = 0; wv < 3; wv++) {
#pragma unroll
            for (int c = 0; c < 4; c++) {
                accA[c] += redbuf[wv][c][lane];
                accJ[c] += redbuf[wv][4 + c][lane];
            }
            accZA += redbuf[wv][8][lane];
            accZJ += redbuf[wv][9][lane];
        }
        float invA[4], invJ[4];
#pragma unroll
        for (int r = 0; r < 4; r++) {
            invA[r] = 1.f / accZA[r];
            invJ[r] = 1.f / accZJ[r];
        }
#pragma unroll
        for (int dd = 0; dd < 4; dd++) {
            int d = dd * 16 + m;              // C-frag col = lane&15
            float l0 = lambda_params[d * 2];
            float l1 = lambda_params[d * 2 + 1];
            float e0 = __expf(l0), e1 = __expf(l1);
            float inv = 1.f / (e0 + e1);
            float la = e0 * inv, lj = e1 * inv;
#pragma unroll
            for (int r = 0; r < 4; r++) {
                int i = rowbase + q * 4 + r;  // C-frag row = quad*4 + reg
                size_t off = (size_t)(b * N_ + i) * D_ + d;
                out[off] = la * accA[dd][r] * invA[r] + lj * accJ[dd][r] * invJ[r] + feats[off];
            }
        }
    }
}

extern "C" void kernel_launch(void* const* d_in, const int* in_sizes, int n_in,
                              void* d_out, int out_size, void* d_ws, size_t ws_size,
                              hipStream_t stream) {
    const int* mask_adj = (const int*)d_in[0];
    const int* mask_job = (const int*)d_in[1];
    const int* batch_idxes = (const int*)d_in[2];
    const float* feats = (const float*)d_in[3];
    const float* W = (const float*)d_in[4];
    const float* attn_src = (const float*)d_in[5];
    const float* attn_dst = (const float*)d_in[6];
    const float* lambda_params = (const float*)d_in[7];
    float* out = (float*)d_out;

    // workspace layout (10.2 MB):
    //   hT   : 2 MB bf16        a_src/F1/F2 : 3 x 64 KB f32
    //   cmA  : 4 MB bitmask     cmJ         : 4 MB bitmask
    unsigned short* hT = (unsigned short*)d_ws;
    float* a_src = (float*)((char*)d_ws + (size_t)B_ * 64 * N_ * 2);
    float* F1 = a_src + B_ * N_;
    float* F2 = F1 + B_ * N_;
    unsigned char* cmA = (unsigned char*)d_ws + (size_t)B_ * 64 * N_ * 2 + 3 * (size_t)B_ * N_ * 4;
    unsigned char* cmJ = cmA + (size_t)B_ * N_ * N_ / 8;

    pack_kernel<<<(B_ * N_ * N_ / 32) / 256, 256, 0, stream>>>(
        mask_adj, mask_job, (unsigned*)cmA, (unsigned*)cmJ);
    prep_kernel<<<B_ * (N_ / 32), 256, 0, stream>>>(feats, W, attn_src, attn_dst,
                                                    hT, a_src, F1, F2);
    attn_kernel<<<B_ * (N_ / 16), 256, 0, stream>>>(cmA, cmJ, batch_idxes,
                                                    hT, a_src, F1, F2, feats,
                                                    lambda_params, out);
}

// Round 6
// 339.171 us; speedup vs baseline: 1.0304x; 1.0304x over previous
//
#include <hip/hip_runtime.h>

#define B_ 8
#define N_ 2048
#define D_ 64
#define PKT 128   // pack_kernel threads per block (2 waves)

typedef __attribute__((ext_vector_type(8))) short bf16x8;
typedef __attribute__((ext_vector_type(4))) float f32x4;

__device__ inline unsigned short f32_bf16_rne(float f) {
    unsigned u = __float_as_uint(f);
    u += 0x7fffu + ((u >> 16) & 1u);
    return (unsigned short)(u >> 16);
}

// packed f32x2 -> bf16x2 (RNE), one instruction; no builtin on gfx950 (T12)
__device__ inline unsigned cvt_pk_bf16(float lo, float hi) {
    unsigned r;
    asm("v_cvt_pk_bf16_f32 %0, %1, %2" : "=v"(r) : "v"(lo), "v"(hi));
    return r;
}

// Kernel 0: pack int32 0/1 masks into bitmasks via global->LDS direct loads.
// Rounds 3-5 proved hipcc's register allocator refuses a VGPR landing zone
// (VGPR_Count 16/32 -> ~2-4 loads in flight -> latency-bound, 2.5 TB/s eff).
// global_load_lds needs NO destination VGPRs: outstanding loads sit in the
// vmcnt queue, so each wave legally holds 16 KB in flight (16 x 1 KB).
// Layout is fully linear (dest = uniform base + lane*16, source lane-contiguous
// -> coalesced; rule-21 safe: no swizzle on either side). LDS read-back uses a
// rotated slot order (slot=(k+t)&7) so each ds_read_b128 spreads 64 lanes
// uniformly over the 8 bank-groups (structural 8-cycle minimum, no conflicts).
// Bit semantics identical to round-5 (verified): bit p of word g = mask[g*32+p]&1.
__global__ __launch_bounds__(PKT) void pack_kernel(
    const int* __restrict__ mA, const int* __restrict__ mJ,
    unsigned* __restrict__ cA, unsigned* __restrict__ cJ) {
    __shared__ int ldsA[PKT * 32];   // 16 KB
    __shared__ int ldsJ[PKT * 32];   // 16 KB
    const int t = threadIdx.x;
    const int wv = t >> 6, lane = t & 63;
    const size_t blkbase = (size_t)blockIdx.x * (PKT * 32);

    typedef const __attribute__((address_space(1))) void* gp_t;
    typedef __attribute__((address_space(3))) void* sp_t;

    // each wave stages its 8 KB half of both mask regions: 16 x global_load_lds(16B/lane)
#pragma unroll
    for (int k = 0; k < 8; k++) {
        const int idx = wv * 2048 + k * 256;          // int index, wave-uniform part
        __builtin_amdgcn_global_load_lds((gp_t)(mA + blkbase + idx + lane * 4),
                                         (sp_t)&ldsA[idx], 16, 0, 0);
        __builtin_amdgcn_global_load_lds((gp_t)(mJ + blkbase + idx + lane * 4),
                                         (sp_t)&ldsJ[idx], 16, 0, 0);
    }
    __syncthreads();   // drains vmcnt(0) + barrier: LDS valid

    unsigned wa = 0, wj = 0;
#pragma unroll
    for (int k = 0; k < 8; k++) {
        const int s_ = (k + t) & 7;                   // rotated slot within this thread's row
        int4 va = *(const int4*)&ldsA[t * 32 + s_ * 4];
        int4 vj = *(const int4*)&ldsJ[t * 32 + s_ * 4];
        const int sh = 4 * s_;
        wa |= (((unsigned)(va.x & 1)) | ((unsigned)(va.y & 1) << 1) |
               ((unsigned)(va.z & 1) << 2) | ((unsigned)(va.w & 1) << 3)) << sh;
        wj |= (((unsigned)(vj.x & 1)) | ((unsigned)(vj.y & 1) << 1) |
               ((unsigned)(vj.z & 1) << 2) | ((unsigned)(vj.w & 1) << 3)) << sh;
    }
    cA[(size_t)blockIdx.x * PKT + t] = wa;
    cJ[(size_t)blockIdx.x * PKT + t] = wj;
}

// Kernel A: h = feats @ W^T (fp32), a_src reduction, exp tables for the dst side,
// store hT[b][d][j] as bf16. 512 blocks x 256 threads; block = 32 rows of one batch.
__global__ __launch_bounds__(256) void prep_kernel(
    const float* __restrict__ feats, const float* __restrict__ W,
    const float* __restrict__ attn_src, const float* __restrict__ attn_dst,
    unsigned short* __restrict__ hT, float* __restrict__ a_src,
    float* __restrict__ F1, float* __restrict__ F2) {
    __shared__ float w_lds[64 * 65];          // padded: bank = (o+d)%32, conflict-free
    __shared__ float f_lds[32 * 64];
    __shared__ unsigned short hT_lds[64 * 40]; // row stride 40 ushorts = 80B (16B aligned)

    const int t = threadIdx.x;
    const int b = blockIdx.x >> 6;            // 64 row-tiles per batch
    const int rowbase = (blockIdx.x & 63) * 32;

    // cooperative load W (64x64) into padded LDS
#pragma unroll
    for (int k = 0; k < 4; k++) {
        int lin = (k * 256 + t) * 4;
        float4 v = *(const float4*)(W + lin);
        int o = lin >> 6, d = lin & 63;
        float* p = &w_lds[o * 65 + d];
        p[0] = v.x; p[1] = v.y; p[2] = v.z; p[3] = v.w;
    }
    // cooperative load feats tile (32x64), linear layout
#pragma unroll
    for (int k = 0; k < 2; k++) {
        int lin = (k * 256 + t) * 4;
        float4 v = *(const float4*)(feats + (size_t)(b * N_ + rowbase) * D_ + lin);
        float* p = &f_lds[lin];
        p[0] = v.x; p[1] = v.y; p[2] = v.z; p[3] = v.w;
    }
    __syncthreads();

    const int w = t >> 6;     // wave id: rows w*8 .. w*8+7
    const int o = t & 63;     // output channel
    float acc[8] = {0.f, 0.f, 0.f, 0.f, 0.f, 0.f, 0.f, 0.f};
#pragma unroll 8
    for (int d = 0; d < 64; d++) {
        float wv = w_lds[o * 65 + d];
#pragma unroll
        for (int rr = 0; rr < 8; rr++)
            acc[rr] = fmaf(f_lds[(w * 8 + rr) * 64 + d], wv, acc[rr]);
    }
    float as_ = attn_src[o], ad_ = attn_dst[o];
#pragma unroll
    for (int rr = 0; rr < 8; rr++) {
        int row = rowbase + w * 8 + rr;
        float s1 = acc[rr] * as_;
        float s2 = acc[rr] * ad_;
#pragma unroll
        for (int off = 32; off; off >>= 1) {
            s1 += __shfl_xor(s1, off);
            s2 += __shfl_xor(s2, off);
        }
        if (o == 0) {
            a_src[b * N_ + row] = s1;
            F1[b * N_ + row] = __expf(s2);         // exp(a_dst)
            F2[b * N_ + row] = __expf(0.2f * s2);  // exp(0.2*a_dst)
        }
        hT_lds[o * 40 + w * 8 + rr] = f32_bf16_rne(acc[rr]);
    }
    __syncthreads();
    // transposed store: hT[b][d][rowbase..rowbase+32)
    const int d = t >> 2, seg = t & 3;
    uint4 vv = *(const uint4*)(&hT_lds[d * 40 + seg * 8]);
    *(uint4*)(hT + ((size_t)(b * 64 + d) * N_ + rowbase + seg * 8)) = vv;
}

// Kernel B: masked dual-softmax attention via bf16 MFMA.
// Reads 1-bit packed masks: each lane pulls its whole 512-col slice (16 words
// per mask, L2-resident after pack_kernel) UP FRONT; per step the 8 predicate
// bits are a shift+mask of word[st]. Only per-step loads are F1/F2 (16 KB/batch,
// L1-resident) and hT (256 KB/batch, L2-resident). ~44 us in round 3/5.
__global__ __launch_bounds__(256, 3) void attn_kernel(
    const unsigned char* __restrict__ cmA, const unsigned char* __restrict__ cmJ,
    const int* __restrict__ batch_idxes,
    const unsigned short* __restrict__ hT, const float* __restrict__ a_src,
    const float* __restrict__ F1, const float* __restrict__ F2,
    const float* __restrict__ feats, const float* __restrict__ lambda_params,
    float* __restrict__ out) {
    __shared__ f32x4 redbuf[3][10][64];       // waves 1..3 partial state: 30 KB

    const int t = threadIdx.x;
    const int b = blockIdx.x >> 7;            // 128 row-tiles per batch
    const int rowbase = (blockIdx.x & 127) * 16;
    const int wid = t >> 6, lane = t & 63;
    const int m = lane & 15, q = lane >> 4;
    const int i_a = rowbase + m;              // A-fragment row this lane owns

    int bi = batch_idxes[b];
    bi = (bi < 0) ? 0 : ((bi >= B_) ? (B_ - 1) : bi);

    const int jb = wid * 512 + q * 8;         // lane's column base within the row
    const float* f1p = F1 + b * N_ + jb;
    const float* f2p = F2 + b * N_ + jb;
    const unsigned short* hp0 = hT + (size_t)b * 64 * N_ + (size_t)m * N_ + jb;
    const unsigned short* hp1 = hp0 + 16 * N_;
    const unsigned short* hp2 = hp0 + 32 * N_;
    const unsigned short* hp3 = hp0 + 48 * N_;

    // upfront bitmask load: 64 B per mask covers all 16 steps of this lane's slice
    union { uint4 v[4]; unsigned w[16]; } WA, WJ;
    {
        const uint4* pA = (const uint4*)(cmA + ((size_t)bi * N_ + i_a) * (N_ / 8) + wid * 64);
        const uint4* pJ = (const uint4*)(cmJ + ((size_t)bi * N_ + i_a) * (N_ / 8) + wid * 64);
        WA.v[0] = pA[0]; WA.v[1] = pA[1]; WA.v[2] = pA[2]; WA.v[3] = pA[3];
        WJ.v[0] = pJ[0]; WJ.v[1] = pJ[1]; WJ.v[2] = pJ[2]; WJ.v[3] = pJ[3];
    }

    const float s = a_src[b * N_ + i_a];
    const float cmpT = __expf(-s);            // exp(d) >= exp(-s)  <=>  e >= 0
    const float cT = __expf(-0.8f * s);       // exp(0.2e - s) = cT * exp(0.2 d)

    f32x4 accA[4], accJ[4], accZA, accZJ;
    const f32x4 z4 = {0.f, 0.f, 0.f, 0.f};
#pragma unroll
    for (int dd = 0; dd < 4; dd++) { accA[dd] = z4; accJ[dd] = z4; }
    accZA = z4; accZJ = z4;
    bf16x8 ones;
#pragma unroll
    for (int i = 0; i < 8; i++) ones[i] = (short)0x3F80;  // bf16(1.0)

#pragma unroll
    for (int st = 0; st < 16; st++) {
        const int off = st * 32;              // 128B/step immediate offsets
        float4 g0 = *(const float4*)(f1p + off);
        float4 g1 = *(const float4*)(f1p + off + 4);
        float4 h0 = *(const float4*)(f2p + off);
        float4 h1 = *(const float4*)(f2p + off + 4);
        bf16x8 fb0 = *(const bf16x8*)(hp0 + off);
        bf16x8 fb1 = *(const bf16x8*)(hp1 + off);
        bf16x8 fb2 = *(const bf16x8*)(hp2 + off);
        bf16x8 fb3 = *(const bf16x8*)(hp3 + off);

        float f1v[8] = {g0.x, g0.y, g0.z, g0.w, g1.x, g1.y, g1.z, g1.w};
        float f2v[8] = {h0.x, h0.y, h0.z, h0.w, h1.x, h1.y, h1.z, h1.w};
        const unsigned byteA = (WA.w[st] >> (q * 8)) & 0xffu;
        const unsigned byteJ = (WJ.w[st] >> (q * 8)) & 0xffu;

        unsigned ua[4], uj[4];
#pragma unroll
        for (int wp = 0; wp < 4; wp++) {
            float p0 = (f1v[2 * wp] >= cmpT) ? f1v[2 * wp] : cT * f2v[2 * wp];
            float p1 = (f1v[2 * wp + 1] >= cmpT) ? f1v[2 * wp + 1] : cT * f2v[2 * wp + 1];
            float pa0 = ((byteA >> (2 * wp)) & 1u) ? p0 : 0.f;
            float pa1 = ((byteA >> (2 * wp + 1)) & 1u) ? p1 : 0.f;
            float pj0 = ((byteJ >> (2 * wp)) & 1u) ? p0 : 0.f;
            float pj1 = ((byteJ >> (2 * wp + 1)) & 1u) ? p1 : 0.f;
            ua[wp] = cvt_pk_bf16(pa0, pa1);
            uj[wp] = cvt_pk_bf16(pj0, pj1);
        }
        union { uint4 u; bf16x8 v; } fa_, fj_;
        fa_.u = make_uint4(ua[0], ua[1], ua[2], ua[3]);
        fj_.u = make_uint4(uj[0], uj[1], uj[2], uj[3]);
        bf16x8 fa = fa_.v, fj = fj_.v;

        // softmax denominators ride the MFMA pipe (B = ones)
        accZA = __builtin_amdgcn_mfma_f32_16x16x32_bf16(fa, ones, accZA, 0, 0, 0);
        accZJ = __builtin_amdgcn_mfma_f32_16x16x32_bf16(fj, ones, accZJ, 0, 0, 0);
        accA[0] = __builtin_amdgcn_mfma_f32_16x16x32_bf16(fa, fb0, accA[0], 0, 0, 0);
        accJ[0] = __builtin_amdgcn_mfma_f32_16x16x32_bf16(fj, fb0, accJ[0], 0, 0, 0);
        accA[1] = __builtin_amdgcn_mfma_f32_16x16x32_bf16(fa, fb1, accA[1], 0, 0, 0);
        accJ[1] = __builtin_amdgcn_mfma_f32_16x16x32_bf16(fj, fb1, accJ[1], 0, 0, 0);
        accA[2] = __builtin_amdgcn_mfma_f32_16x16x32_bf16(fa, fb2, accA[2], 0, 0, 0);
        accJ[2] = __builtin_amdgcn_mfma_f32_16x16x32_bf16(fj, fb2, accJ[2], 0, 0, 0);
        accA[3] = __builtin_amdgcn_mfma_f32_16x16x32_bf16(fa, fb3, accA[3], 0, 0, 0);
        accJ[3] = __builtin_amdgcn_mfma_f32_16x16x32_bf16(fj, fb3, accJ[3], 0, 0, 0);
    }

    // cross-wave reduction of j-slice partials (40 f32 per lane = 10 f32x4 chunks)
    if (wid) {
#pragma unroll
        for (int c = 0; c < 4; c++) {
            redbuf[wid - 1][c][lane] = accA[c];
            redbuf[wid - 1][4 + c][lane] = accJ[c];
        }
        redbuf[wid - 1][8][lane] = accZA;
        redbuf[wid - 1][9][lane] = accZJ;
    }
    __syncthreads();
    if (wid == 0) {
#pragma unroll
        for (int wv = 0; wv < 3; wv++) {
#pragma unroll
            for (int c = 0; c < 4; c++) {
                accA[c] += redbuf[wv][c][lane];
                accJ[c] += redbuf[wv][4 + c][lane];
            }
            accZA += redbuf[wv][8][lane];
            accZJ += redbuf[wv][9][lane];
        }
        float invA[4], invJ[4];
#pragma unroll
        for (int r = 0; r < 4; r++) {
            invA[r] = 1.f / accZA[r];
            invJ[r] = 1.f / accZJ[r];
        }
#pragma unroll
        for (int dd = 0; dd < 4; dd++) {
            int d = dd * 16 + m;              // C-frag col = lane&15
            float l0 = lambda_params[d * 2];
            float l1 = lambda_params[d * 2 + 1];
            float e0 = __expf(l0), e1 = __expf(l1);
            float inv = 1.f / (e0 + e1);
            float la = e0 * inv, lj = e1 * inv;
#pragma unroll
            for (int r = 0; r < 4; r++) {
                int i = rowbase + q * 4 + r;  // C-frag row = quad*4 + reg
                size_t off = (size_t)(b * N_ + i) * D_ + d;
                out[off] = la * accA[dd][r] * invA[r] + lj * accJ[dd][r] * invJ[r] + feats[off];
            }
        }
    }
}

extern "C" void kernel_launch(void* const* d_in, const int* in_sizes, int n_in,
                              void* d_out, int out_size, void* d_ws, size_t ws_size,
                              hipStream_t stream) {
    const int* mask_adj = (const int*)d_in[0];
    const int* mask_job = (const int*)d_in[1];
    const int* batch_idxes = (const int*)d_in[2];
    const float* feats = (const float*)d_in[3];
    const float* W = (const float*)d_in[4];
    const float* attn_src = (const float*)d_in[5];
    const float* attn_dst = (const float*)d_in[6];
    const float* lambda_params = (const float*)d_in[7];
    float* out = (float*)d_out;

    // workspace layout (10.2 MB):
    //   hT   : 2 MB bf16        a_src/F1/F2 : 3 x 64 KB f32
    //   cmA  : 4 MB bitmask     cmJ         : 4 MB bitmask
    unsigned short* hT = (unsigned short*)d_ws;
    float* a_src = (float*)((char*)d_ws + (size_t)B_ * 64 * N_ * 2);
    float* F1 = a_src + B_ * N_;
    float* F2 = F1 + B_ * N_;
    unsigned char* cmA = (unsigned char*)d_ws + (size_t)B_ * 64 * N_ * 2 + 3 * (size_t)B_ * N_ * 4;
    unsigned char* cmJ = cmA + (size_t)B_ * N_ * N_ / 8;

    pack_kernel<<<(B_ * N_ * N_ / 32) / PKT, PKT, 0, stream>>>(
        mask_adj, mask_job, (unsigned*)cmA, (unsigned*)cmJ);
    prep_kernel<<<B_ * (N_ / 32), 256, 0, stream>>>(feats, W, attn_src, attn_dst,
                                                    hT, a_src, F1, F2);
    attn_kernel<<<B_ * (N_ / 16), 256, 0, stream>>>(cmA, cmJ, batch_idxes,
                                                    hT, a_src, F1, F2, feats,
                                                    lambda_params, out);
}

// Round 7
// 323.522 us; speedup vs baseline: 1.0802x; 1.0484x over previous
//
#include <hip/hip_runtime.h>

#define B_ 8
#define N_ 2048
#define D_ 64

typedef __attribute__((ext_vector_type(8))) short bf16x8;
typedef __attribute__((ext_vector_type(4))) float f32x4;

__device__ inline unsigned short f32_bf16_rne(float f) {
    unsigned u = __float_as_uint(f);
    u += 0x7fffu + ((u >> 16) & 1u);
    return (unsigned short)(u >> 16);
}

// packed f32x2 -> bf16x2 (RNE), one instruction; no builtin on gfx950 (T12)
__device__ inline unsigned cvt_pk_bf16(float lo, float hi) {
    unsigned r;
    asm("v_cvt_pk_bf16_f32 %0, %1, %2" : "=v"(r) : "v"(lo), "v"(hi));
    return r;
}

// Kernel A: h = feats @ W^T (fp32), a_src reduction, exp tables for the dst side,
// store hT[b][d][j] as bf16. 512 blocks x 256 threads; block = 32 rows of one batch.
__global__ __launch_bounds__(256) void prep_kernel(
    const float* __restrict__ feats, const float* __restrict__ W,
    const float* __restrict__ attn_src, const float* __restrict__ attn_dst,
    unsigned short* __restrict__ hT, float* __restrict__ a_src,
    float* __restrict__ F1, float* __restrict__ F2) {
    __shared__ float w_lds[64 * 65];          // padded: bank = (o+d)%32, conflict-free
    __shared__ float f_lds[32 * 64];
    __shared__ unsigned short hT_lds[64 * 40]; // row stride 40 ushorts = 80B (16B aligned)

    const int t = threadIdx.x;
    const int b = blockIdx.x >> 6;            // 64 row-tiles per batch
    const int rowbase = (blockIdx.x & 63) * 32;

#pragma unroll
    for (int k = 0; k < 4; k++) {
        int lin = (k * 256 + t) * 4;
        float4 v = *(const float4*)(W + lin);
        int o = lin >> 6, d = lin & 63;
        float* p = &w_lds[o * 65 + d];
        p[0] = v.x; p[1] = v.y; p[2] = v.z; p[3] = v.w;
    }
#pragma unroll
    for (int k = 0; k < 2; k++) {
        int lin = (k * 256 + t) * 4;
        float4 v = *(const float4*)(feats + (size_t)(b * N_ + rowbase) * D_ + lin);
        float* p = &f_lds[lin];
        p[0] = v.x; p[1] = v.y; p[2] = v.z; p[3] = v.w;
    }
    __syncthreads();

    const int w = t >> 6;     // wave id: rows w*8 .. w*8+7
    const int o = t & 63;     // output channel
    float acc[8] = {0.f, 0.f, 0.f, 0.f, 0.f, 0.f, 0.f, 0.f};
#pragma unroll 8
    for (int d = 0; d < 64; d++) {
        float wv = w_lds[o * 65 + d];
#pragma unroll
        for (int rr = 0; rr < 8; rr++)
            acc[rr] = fmaf(f_lds[(w * 8 + rr) * 64 + d], wv, acc[rr]);
    }
    float as_ = attn_src[o], ad_ = attn_dst[o];
#pragma unroll
    for (int rr = 0; rr < 8; rr++) {
        int row = rowbase + w * 8 + rr;
        float s1 = acc[rr] * as_;
        float s2 = acc[rr] * ad_;
#pragma unroll
        for (int off = 32; off; off >>= 1) {
            s1 += __shfl_xor(s1, off);
            s2 += __shfl_xor(s2, off);
        }
        if (o == 0) {
            a_src[b * N_ + row] = s1;
            F1[b * N_ + row] = __expf(s2);         // exp(a_dst)
            F2[b * N_ + row] = __expf(0.2f * s2);  // exp(0.2*a_dst)
        }
        hT_lds[o * 40 + w * 8 + rr] = f32_bf16_rne(acc[rr]);
    }
    __syncthreads();
    const int d = t >> 2, seg = t & 3;
    uint4 vv = *(const uint4*)(&hT_lds[d * 40 + seg * 8]);
    *(uint4*)(hT + ((size_t)(b * 64 + d) * N_ + rowbase + seg * 8)) = vv;
}

// Kernel B: FUSED masked dual-softmax attention. Evidence from rounds 0-6: the
// 268 MB int32 mask stream runs at ~2.5-2.8 TB/s effective no matter the kernel
// structure (5 independent implementations converge there), i.e. ~95-100 us.
// The split pack(98)+attn(44) serializes at the launch boundary; this kernel
// consumes the masks DIRECTLY and hides all compute under the stream:
//  - per wave, per 32-col step: masks staged by 4x global_load_lds (1 KB each,
//    zero VGPR landing cost — the trick rounds 3-5 proved VGPRs can't do) into
//    a wave-PRIVATE 2x2KB double buffer -> no __syncthreads in the loop.
//  - source lane-map (row=lane&15, gran=lane>>4) makes LDS layout g*256+r*16:
//    MFMA-side int4 reads are 2-way-bank-free with zero swizzle (rule 21:
//    both sides linear).
//  - counted wait: stage(t+1)'s 4 instrs are issued before the wait, so
//    s_waitcnt vmcnt(4) proves stage(t) retired (FIFO vmcnt, m135) regardless
//    of compiler-scheduled direct loads. sched_barrier(0) after it (rule 18).
//  - epilogue cross-wave reduction in two 5-chunk rounds -> redbuf 15 KB;
//    total LDS 47 KB -> 3 blocks/CU, 12 waves, ~48 KB mask loads in flight.
__global__ __launch_bounds__(256, 3) void attn_kernel(
    const int* __restrict__ mask_adj, const int* __restrict__ mask_job,
    const int* __restrict__ batch_idxes,
    const unsigned short* __restrict__ hT, const float* __restrict__ a_src,
    const float* __restrict__ F1, const float* __restrict__ F2,
    const float* __restrict__ feats, const float* __restrict__ lambda_params,
    float* __restrict__ out) {
    __shared__ int ldsA[4][2][512];           // [wave][buf][2 KB of ints]
    __shared__ int ldsJ[4][2][512];
    __shared__ f32x4 redbuf[3][5][64];        // 15 KB, two-round reduction

    const int t = threadIdx.x;
    const int b = blockIdx.x >> 7;            // 128 row-tiles per batch
    const int rowbase = (blockIdx.x & 127) * 16;
    const int wid = t >> 6, lane = t & 63;
    const int m = lane & 15, q = lane >> 4;
    const int i_a = rowbase + m;              // A-fragment row this lane owns

    int bi = batch_idxes[b];
    bi = (bi < 0) ? 0 : ((bi >= B_) ? (B_ - 1) : bi);

    // staging role: lane covers (row = lane&15, granule = lane>>4)
    const int srow = lane & 15, sgran = lane >> 4;
    const int* rA = mask_adj + ((size_t)bi * N_ + rowbase + srow) * N_ + wid * 512 + sgran * 4;
    const int* rJ = mask_job + ((size_t)bi * N_ + rowbase + srow) * N_ + wid * 512 + sgran * 4;

    typedef const __attribute__((address_space(1))) void* gp_t;
    typedef __attribute__((address_space(3))) void* sp_t;

    const int jb = wid * 512 + q * 8;         // lane's column base within the row
    const float* f1p = F1 + b * N_ + jb;
    const float* f2p = F2 + b * N_ + jb;
    const unsigned short* hp0 = hT + (size_t)b * 64 * N_ + (size_t)m * N_ + jb;
    const unsigned short* hp1 = hp0 + 16 * N_;
    const unsigned short* hp2 = hp0 + 32 * N_;
    const unsigned short* hp3 = hp0 + 48 * N_;

    const float s = a_src[b * N_ + i_a];
    const float cmpT = __expf(-s);            // exp(d) >= exp(-s)  <=>  e >= 0
    const float cT = __expf(-0.8f * s);       // exp(0.2e - s) = cT * exp(0.2 d)

    f32x4 accA[4], accJ[4], accZA, accZJ;
    const f32x4 z4 = {0.f, 0.f, 0.f, 0.f};
#pragma unroll
    for (int dd = 0; dd < 4; dd++) { accA[dd] = z4; accJ[dd] = z4; }
    accZA = z4; accZJ = z4;
    bf16x8 ones;
#pragma unroll
    for (int i = 0; i < 8; i++) ones[i] = (short)0x3F80;  // bf16(1.0)

    auto stage = [&](int tt, int cc) {
        // instr k covers granules k*4+sgran: source +k*16 ints, dest +k*256 ints
        __builtin_amdgcn_global_load_lds((gp_t)(rA + tt * 32),      (sp_t)&ldsA[wid][cc][0],   16, 0, 0);
        __builtin_amdgcn_global_load_lds((gp_t)(rA + tt * 32 + 16), (sp_t)&ldsA[wid][cc][256], 16, 0, 0);
        __builtin_amdgcn_global_load_lds((gp_t)(rJ + tt * 32),      (sp_t)&ldsJ[wid][cc][0],   16, 0, 0);
        __builtin_amdgcn_global_load_lds((gp_t)(rJ + tt * 32 + 16), (sp_t)&ldsJ[wid][cc][256], 16, 0, 0);
    };

    stage(0, 0);

#pragma unroll
    for (int st = 0; st < 16; st++) {
        const int cc = st & 1;
        if (st < 15) {
            stage(st + 1, cc ^ 1);
            // stage(st)'s 4 loads are strictly older than stage(st+1)'s 4:
            // vmcnt(4) => stage(st) retired, buf[cc] valid.
            asm volatile("s_waitcnt vmcnt(4)" ::: "memory");
        } else {
            asm volatile("s_waitcnt vmcnt(0)" ::: "memory");
        }
        __builtin_amdgcn_sched_barrier(0);

        // conflict-free LDS reads: addr = g*256B + m*16B, g = 2q / 2q+1
        const int4 iA0 = *(const int4*)&ldsA[wid][cc][(2 * q) * 64 + m * 4];
        const int4 iA1 = *(const int4*)&ldsA[wid][cc][(2 * q + 1) * 64 + m * 4];
        const int4 iJ0 = *(const int4*)&ldsJ[wid][cc][(2 * q) * 64 + m * 4];
        const int4 iJ1 = *(const int4*)&ldsJ[wid][cc][(2 * q + 1) * 64 + m * 4];

        const int off = st * 32;              // 128B/step immediate offsets
        float4 g0 = *(const float4*)(f1p + off);
        float4 g1 = *(const float4*)(f1p + off + 4);
        float4 h0 = *(const float4*)(f2p + off);
        float4 h1 = *(const float4*)(f2p + off + 4);
        bf16x8 fb0 = *(const bf16x8*)(hp0 + off);
        bf16x8 fb1 = *(const bf16x8*)(hp1 + off);
        bf16x8 fb2 = *(const bf16x8*)(hp2 + off);
        bf16x8 fb3 = *(const bf16x8*)(hp3 + off);

        int ma[8] = {iA0.x, iA0.y, iA0.z, iA0.w, iA1.x, iA1.y, iA1.z, iA1.w};
        int mj[8] = {iJ0.x, iJ0.y, iJ0.z, iJ0.w, iJ1.x, iJ1.y, iJ1.z, iJ1.w};
        float f1v[8] = {g0.x, g0.y, g0.z, g0.w, g1.x, g1.y, g1.z, g1.w};
        float f2v[8] = {h0.x, h0.y, h0.z, h0.w, h1.x, h1.y, h1.z, h1.w};

        unsigned ua[4], uj[4];
#pragma unroll
        for (int wp = 0; wp < 4; wp++) {
            float p0 = (f1v[2 * wp] >= cmpT) ? f1v[2 * wp] : cT * f2v[2 * wp];
            float p1 = (f1v[2 * wp + 1] >= cmpT) ? f1v[2 * wp + 1] : cT * f2v[2 * wp + 1];
            float pa0 = (ma[2 * wp] == 1) ? p0 : 0.f;
            float pa1 = (ma[2 * wp + 1] == 1) ? p1 : 0.f;
            float pj0 = (mj[2 * wp] == 1) ? p0 : 0.f;
            float pj1 = (mj[2 * wp + 1] == 1) ? p1 : 0.f;
            ua[wp] = cvt_pk_bf16(pa0, pa1);
            uj[wp] = cvt_pk_bf16(pj0, pj1);
        }
        union { uint4 u; bf16x8 v; } fa_, fj_;
        fa_.u = make_uint4(ua[0], ua[1], ua[2], ua[3]);
        fj_.u = make_uint4(uj[0], uj[1], uj[2], uj[3]);
        bf16x8 fa = fa_.v, fj = fj_.v;

        // softmax denominators ride the MFMA pipe (B = ones)
        accZA = __builtin_amdgcn_mfma_f32_16x16x32_bf16(fa, ones, accZA, 0, 0, 0);
        accZJ = __builtin_amdgcn_mfma_f32_16x16x32_bf16(fj, ones, accZJ, 0, 0, 0);
        accA[0] = __builtin_amdgcn_mfma_f32_16x16x32_bf16(fa, fb0, accA[0], 0, 0, 0);
        accJ[0] = __builtin_amdgcn_mfma_f32_16x16x32_bf16(fj, fb0, accJ[0], 0, 0, 0);
        accA[1] = __builtin_amdgcn_mfma_f32_16x16x32_bf16(fa, fb1, accA[1], 0, 0, 0);
        accJ[1] = __builtin_amdgcn_mfma_f32_16x16x32_bf16(fj, fb1, accJ[1], 0, 0, 0);
        accA[2] = __builtin_amdgcn_mfma_f32_16x16x32_bf16(fa, fb2, accA[2], 0, 0, 0);
        accJ[2] = __builtin_amdgcn_mfma_f32_16x16x32_bf16(fj, fb2, accJ[2], 0, 0, 0);
        accA[3] = __builtin_amdgcn_mfma_f32_16x16x32_bf16(fa, fb3, accA[3], 0, 0, 0);
        accJ[3] = __builtin_amdgcn_mfma_f32_16x16x32_bf16(fj, fb3, accJ[3], 0, 0, 0);
    }

    // cross-wave reduction, two rounds of 5 chunks (redbuf = 15 KB)
    if (wid) {
#pragma unroll
        for (int c = 0; c < 4; c++) redbuf[wid - 1][c][lane] = accA[c];
        redbuf[wid - 1][4][lane] = accZA;
    }
    __syncthreads();
    if (wid == 0) {
#pragma unroll
        for (int wv = 0; wv < 3; wv++) {
#pragma unroll
            for (int c = 0; c < 4; c++) accA[c] += redbuf[wv][c][lane];
            accZA += redbuf[wv][4][lane];
        }
    }
    __syncthreads();                          // wave 0 done reading round 1
    if (wid) {
#pragma unroll
        for (int c = 0; c < 4; c++) redbuf[wid - 1][c][lane] = accJ[c];
        redbuf[wid - 1][4][lane] = accZJ;
    }
    __syncthreads();
    if (wid == 0) {
#pragma unroll
        for (int wv = 0; wv < 3; wv++) {
#pragma unroll
            for (int c = 0; c < 4; c++) accJ[c] += redbuf[wv][c][lane];
            accZJ += redbuf[wv][4][lane];
        }
        float invA[4], invJ[4];
#pragma unroll
        for (int r = 0; r < 4; r++) {
            invA[r] = 1.f / accZA[r];
            invJ[r] = 1.f / accZJ[r];
        }
#pragma unroll
        for (int dd = 0; dd < 4; dd++) {
            int d = dd * 16 + m;              // C-frag col = lane&15
            float l0 = lambda_params[d * 2];
            float l1 = lambda_params[d * 2 + 1];
            float e0 = __expf(l0), e1 = __expf(l1);
            float inv = 1.f / (e0 + e1);
            float la = e0 * inv, lj = e1 * inv;
#pragma unroll
            for (int r = 0; r < 4; r++) {
                int i = rowbase + q * 4 + r;  // C-frag row = quad*4 + reg
                size_t off = (size_t)(b * N_ + i) * D_ + d;
                out[off] = la * accA[dd][r] * invA[r] + lj * accJ[dd][r] * invJ[r] + feats[off];
            }
        }
    }
}

extern "C" void kernel_launch(void* const* d_in, const int* in_sizes, int n_in,
                              void* d_out, int out_size, void* d_ws, size_t ws_size,
                              hipStream_t stream) {
    const int* mask_adj = (const int*)d_in[0];
    const int* mask_job = (const int*)d_in[1];
    const int* batch_idxes = (const int*)d_in[2];
    const float* feats = (const float*)d_in[3];
    const float* W = (const float*)d_in[4];
    const float* attn_src = (const float*)d_in[5];
    const float* attn_dst = (const float*)d_in[6];
    const float* lambda_params = (const float*)d_in[7];
    float* out = (float*)d_out;

    // workspace: hT 2 MB bf16, a_src/F1/F2 3 x 64 KB f32
    unsigned short* hT = (unsigned short*)d_ws;
    float* a_src = (float*)((char*)d_ws + (size_t)B_ * 64 * N_ * 2);
    float* F1 = a_src + B_ * N_;
    float* F2 = F1 + B_ * N_;

    prep_kernel<<<B_ * (N_ / 32), 256, 0, stream>>>(feats, W, attn_src, attn_dst,
                                                    hT, a_src, F1, F2);
    attn_kernel<<<B_ * (N_ / 16), 256, 0, stream>>>(mask_adj, mask_job, batch_idxes,
                                                    hT, a_src, F1, F2, feats,
                                                    lambda_params, out);
}

// Round 8
// 319.467 us; speedup vs baseline: 1.0939x; 1.0127x over previous
//
#include <hip/hip_runtime.h>

#define B_ 8
#define N_ 2048
#define D_ 64

typedef __attribute__((ext_vector_type(8))) short bf16x8;
typedef __attribute__((ext_vector_type(4))) float f32x4;
typedef __attribute__((ext_vector_type(4))) int i32x4;

__device__ inline unsigned short f32_bf16_rne(float f) {
    unsigned u = __float_as_uint(f);
    u += 0x7fffu + ((u >> 16) & 1u);
    return (unsigned short)(u >> 16);
}

// packed f32x2 -> bf16x2 (RNE), one instruction; no builtin on gfx950 (T12)
__device__ inline unsigned cvt_pk_bf16(float lo, float hi) {
    unsigned r;
    asm("v_cvt_pk_bf16_f32 %0, %1, %2" : "=v"(r) : "v"(lo), "v"(hi));
    return r;
}

// Kernel A: h = feats @ W^T (fp32), a_src reduction, exp tables for the dst side,
// store hT[b][d][j] as bf16. 512 blocks x 256 threads; block = 32 rows of one batch.
__global__ __launch_bounds__(256) void prep_kernel(
    const float* __restrict__ feats, const float* __restrict__ W,
    const float* __restrict__ attn_src, const float* __restrict__ attn_dst,
    unsigned short* __restrict__ hT, float* __restrict__ a_src,
    float* __restrict__ F1, float* __restrict__ F2) {
    __shared__ float w_lds[64 * 65];          // padded: bank = (o+d)%32, conflict-free
    __shared__ float f_lds[32 * 64];
    __shared__ unsigned short hT_lds[64 * 40]; // row stride 40 ushorts = 80B (16B aligned)

    const int t = threadIdx.x;
    const int b = blockIdx.x >> 6;            // 64 row-tiles per batch
    const int rowbase = (blockIdx.x & 63) * 32;

#pragma unroll
    for (int k = 0; k < 4; k++) {
        int lin = (k * 256 + t) * 4;
        float4 v = *(const float4*)(W + lin);
        int o = lin >> 6, d = lin & 63;
        float* p = &w_lds[o * 65 + d];
        p[0] = v.x; p[1] = v.y; p[2] = v.z; p[3] = v.w;
    }
#pragma unroll
    for (int k = 0; k < 2; k++) {
        int lin = (k * 256 + t) * 4;
        float4 v = *(const float4*)(feats + (size_t)(b * N_ + rowbase) * D_ + lin);
        float* p = &f_lds[lin];
        p[0] = v.x; p[1] = v.y; p[2] = v.z; p[3] = v.w;
    }
    __syncthreads();

    const int w = t >> 6;     // wave id: rows w*8 .. w*8+7
    const int o = t & 63;     // output channel
    float acc[8] = {0.f, 0.f, 0.f, 0.f, 0.f, 0.f, 0.f, 0.f};
#pragma unroll 8
    for (int d = 0; d < 64; d++) {
        float wv = w_lds[o * 65 + d];
#pragma unroll
        for (int rr = 0; rr < 8; rr++)
            acc[rr] = fmaf(f_lds[(w * 8 + rr) * 64 + d], wv, acc[rr]);
    }
    float as_ = attn_src[o], ad_ = attn_dst[o];
#pragma unroll
    for (int rr = 0; rr < 8; rr++) {
        int row = rowbase + w * 8 + rr;
        float s1 = acc[rr] * as_;
        float s2 = acc[rr] * ad_;
#pragma unroll
        for (int off = 32; off; off >>= 1) {
            s1 += __shfl_xor(s1, off);
            s2 += __shfl_xor(s2, off);
        }
        if (o == 0) {
            a_src[b * N_ + row] = s1;
            F1[b * N_ + row] = __expf(s2);         // exp(a_dst)
            F2[b * N_ + row] = __expf(0.2f * s2);  // exp(0.2*a_dst)
        }
        hT_lds[o * 40 + w * 8 + rr] = f32_bf16_rne(acc[rr]);
    }
    __syncthreads();
    const int d = t >> 2, seg = t & 3;
    uint4 vv = *(const uint4*)(&hT_lds[d * 40 + seg * 8]);
    *(uint4*)(hT + ((size_t)(b * 64 + d) * N_ + rowbase + seg * 8)) = vv;
}

// Kernel B: masked dual-softmax attention via bf16 MFMA — exactly the round-2
// structure (verified 115 us) with ONE change: the four mask loads per step are
// NONTEMPORAL. Theory: 5 independent mask-stream kernels converge at 2.4-2.8
// TB/s despite HBM/L2/latency analysis all predicting much higher — the common
// path is the Infinity Cache, which the 268 MB single-use stream transits
// (and self-evicts: buffer > 256 MB L3). nt loads bypass L3 and should move
// the stream to the ~6.3 TB/s HBM path. hT/F1/F2 stay cached (reused data).
__global__ __launch_bounds__(256, 3) void attn_kernel(
    const int* __restrict__ mask_adj, const int* __restrict__ mask_job,
    const int* __restrict__ batch_idxes,
    const unsigned short* __restrict__ hT, const float* __restrict__ a_src,
    const float* __restrict__ F1, const float* __restrict__ F2,
    const float* __restrict__ feats, const float* __restrict__ lambda_params,
    float* __restrict__ out) {
    __shared__ f32x4 redbuf[3][10][64];       // waves 1..3 partial state: 30 KB

    const int t = threadIdx.x;
    const int b = blockIdx.x >> 7;            // 128 row-tiles per batch
    const int rowbase = (blockIdx.x & 127) * 16;
    const int wid = t >> 6, lane = t & 63;
    const int m = lane & 15, q = lane >> 4;
    const int i_a = rowbase + m;              // A-fragment row this lane owns

    int bi = batch_idxes[b];
    bi = (bi < 0) ? 0 : ((bi >= B_) ? (B_ - 1) : bi);

    const int jb = wid * 512 + q * 8;         // lane's column base within the row
    const int* mA = mask_adj + ((size_t)bi * N_ + i_a) * N_ + jb;
    const int* mJ = mask_job + ((size_t)bi * N_ + i_a) * N_ + jb;
    const float* f1p = F1 + b * N_ + jb;
    const float* f2p = F2 + b * N_ + jb;
    const unsigned short* hp0 = hT + (size_t)b * 64 * N_ + (size_t)m * N_ + jb;
    const unsigned short* hp1 = hp0 + 16 * N_;
    const unsigned short* hp2 = hp0 + 32 * N_;
    const unsigned short* hp3 = hp0 + 48 * N_;

    const float s = a_src[b * N_ + i_a];
    const float cmpT = __expf(-s);            // exp(d) >= exp(-s)  <=>  e >= 0
    const float cT = __expf(-0.8f * s);       // exp(0.2e - s) = cT * exp(0.2 d)

    f32x4 accA[4], accJ[4], accZA, accZJ;
    const f32x4 z4 = {0.f, 0.f, 0.f, 0.f};
#pragma unroll
    for (int dd = 0; dd < 4; dd++) { accA[dd] = z4; accJ[dd] = z4; }
    accZA = z4; accZJ = z4;
    bf16x8 ones;
#pragma unroll
    for (int i = 0; i < 8; i++) ones[i] = (short)0x3F80;  // bf16(1.0)

#pragma unroll
    for (int st = 0; st < 16; st++) {
        const int off = st * 32;              // 128B/step immediate offsets
        // single-use mask stream: nontemporal (bypass L3)
        i32x4 a0 = __builtin_nontemporal_load((const i32x4*)(mA + off));
        i32x4 a1 = __builtin_nontemporal_load((const i32x4*)(mA + off + 4));
        i32x4 b0 = __builtin_nontemporal_load((const i32x4*)(mJ + off));
        i32x4 b1 = __builtin_nontemporal_load((const i32x4*)(mJ + off + 4));
        float4 g0 = *(const float4*)(f1p + off);
        float4 g1 = *(const float4*)(f1p + off + 4);
        float4 h0 = *(const float4*)(f2p + off);
        float4 h1 = *(const float4*)(f2p + off + 4);
        bf16x8 fb0 = *(const bf16x8*)(hp0 + off);
        bf16x8 fb1 = *(const bf16x8*)(hp1 + off);
        bf16x8 fb2 = *(const bf16x8*)(hp2 + off);
        bf16x8 fb3 = *(const bf16x8*)(hp3 + off);

        int ma[8] = {a0[0], a0[1], a0[2], a0[3], a1[0], a1[1], a1[2], a1[3]};
        int mj[8] = {b0[0], b0[1], b0[2], b0[3], b1[0], b1[1], b1[2], b1[3]};
        float f1v[8] = {g0.x, g0.y, g0.z, g0.w, g1.x, g1.y, g1.z, g1.w};
        float f2v[8] = {h0.x, h0.y, h0.z, h0.w, h1.x, h1.y, h1.z, h1.w};

        unsigned ua[4], uj[4];
#pragma unroll
        for (int wp = 0; wp < 4; wp++) {
            float p0 = (f1v[2 * wp] >= cmpT) ? f1v[2 * wp] : cT * f2v[2 * wp];
            float p1 = (f1v[2 * wp + 1] >= cmpT) ? f1v[2 * wp + 1] : cT * f2v[2 * wp + 1];
            float pa0 = (ma[2 * wp] == 1) ? p0 : 0.f;
            float pa1 = (ma[2 * wp + 1] == 1) ? p1 : 0.f;
            float pj0 = (mj[2 * wp] == 1) ? p0 : 0.f;
            float pj1 = (mj[2 * wp + 1] == 1) ? p1 : 0.f;
            ua[wp] = cvt_pk_bf16(pa0, pa1);
            uj[wp] = cvt_pk_bf16(pj0, pj1);
        }
        union { uint4 u; bf16x8 v; } fa_, fj_;
        fa_.u = make_uint4(ua[0], ua[1], ua[2], ua[3]);
        fj_.u = make_uint4(uj[0], uj[1], uj[2], uj[3]);
        bf16x8 fa = fa_.v, fj = fj_.v;

        // softmax denominators ride the MFMA pipe (B = ones)
        accZA = __builtin_amdgcn_mfma_f32_16x16x32_bf16(fa, ones, accZA, 0, 0, 0);
        accZJ = __builtin_amdgcn_mfma_f32_16x16x32_bf16(fj, ones, accZJ, 0, 0, 0);
        accA[0] = __builtin_amdgcn_mfma_f32_16x16x32_bf16(fa, fb0, accA[0], 0, 0, 0);
        accJ[0] = __builtin_amdgcn_mfma_f32_16x16x32_bf16(fj, fb0, accJ[0], 0, 0, 0);
        accA[1] = __builtin_amdgcn_mfma_f32_16x16x32_bf16(fa, fb1, accA[1], 0, 0, 0);
        accJ[1] = __builtin_amdgcn_mfma_f32_16x16x32_bf16(fj, fb1, accJ[1], 0, 0, 0);
        accA[2] = __builtin_amdgcn_mfma_f32_16x16x32_bf16(fa, fb2, accA[2], 0, 0, 0);
        accJ[2] = __builtin_amdgcn_mfma_f32_16x16x32_bf16(fj, fb2, accJ[2], 0, 0, 0);
        accA[3] = __builtin_amdgcn_mfma_f32_16x16x32_bf16(fa, fb3, accA[3], 0, 0, 0);
        accJ[3] = __builtin_amdgcn_mfma_f32_16x16x32_bf16(fj, fb3, accJ[3], 0, 0, 0);
    }

    // cross-wave reduction of j-slice partials (40 f32 per lane = 10 f32x4 chunks)
    if (wid) {
#pragma unroll
        for (int c = 0; c < 4; c++) {
            redbuf[wid - 1][c][lane] = accA[c];
            redbuf[wid - 1][4 + c][lane] = accJ[c];
        }
        redbuf[wid - 1][8][lane] = accZA;
        redbuf[wid - 1][9][lane] = accZJ;
    }
    __syncthreads();
    if (wid == 0) {
#pragma unroll
        for (int wv = 0; wv < 3; wv++) {
#pragma unroll
            for (int c = 0; c < 4; c++) {
                accA[c] += redbuf[wv][c][lane];
                accJ[c] += redbuf[wv][4 + c][lane];
            }
            accZA += redbuf[wv][8][lane];
            accZJ += redbuf[wv][9][lane];
        }
        float invA[4], invJ[4];
#pragma unroll
        for (int r = 0; r < 4; r++) {
            invA[r] = 1.f / accZA[r];
            invJ[r] = 1.f / accZJ[r];
        }
#pragma unroll
        for (int dd = 0; dd < 4; dd++) {
            int d = dd * 16 + m;              // C-frag col = lane&15
            float l0 = lambda_params[d * 2];
            float l1 = lambda_params[d * 2 + 1];
            float e0 = __expf(l0), e1 = __expf(l1);
            float inv = 1.f / (e0 + e1);
            float la = e0 * inv, lj = e1 * inv;
#pragma unroll
            for (int r = 0; r < 4; r++) {
                int i = rowbase + q * 4 + r;  // C-frag row = quad*4 + reg
                size_t off = (size_t)(b * N_ + i) * D_ + d;
                out[off] = la * accA[dd][r] * invA[r] + lj * accJ[dd][r] * invJ[r] + feats[off];
            }
        }
    }
}

extern "C" void kernel_launch(void* const* d_in, const int* in_sizes, int n_in,
                              void* d_out, int out_size, void* d_ws, size_t ws_size,
                              hipStream_t stream) {
    const int* mask_adj = (const int*)d_in[0];
    const int* mask_job = (const int*)d_in[1];
    const int* batch_idxes = (const int*)d_in[2];
    const float* feats = (const float*)d_in[3];
    const float* W = (const float*)d_in[4];
    const float* attn_src = (const float*)d_in[5];
    const float* attn_dst = (const float*)d_in[6];
    const float* lambda_params = (const float*)d_in[7];
    float* out = (float*)d_out;

    unsigned short* hT = (unsigned short*)d_ws;                     // B*64*N bf16 = 2 MB
    float* a_src = (float*)((char*)d_ws + (size_t)B_ * 64 * N_ * 2);
    float* F1 = a_src + B_ * N_;
    float* F2 = F1 + B_ * N_;

    prep_kernel<<<B_ * (N_ / 32), 256, 0, stream>>>(feats, W, attn_src, attn_dst,
                                                    hT, a_src, F1, F2);
    attn_kernel<<<B_ * (N_ / 16), 256, 0, stream>>>(mask_adj, mask_job, batch_idxes,
                                                    hT, a_src, F1, F2, feats,
                                                    lambda_params, out);
}